// Round 17
// baseline (657.447 us; speedup 1.0000x reference)
//
#include <hip/hip_runtime.h>
#include <hip/hip_bf16.h>

// SGNO1d: B=16, X=16384, Xp=16386, W=64, H=128, M=64, NB=4.
// MFMA bf16 pipeline. h in two layouts: h16[b][c][XPAD] + hX[b][x][64].
// R17 = R14 structure + k_dft walks chunks 0..127 (8 passes/wg, no straggler)
// with the x=16384,16385 tail folded into k_dft's bx==15 wg epilogue using a
// precomputed tailB table (R16's tail-in-k_ghat added serial latency to an
// undersubscribed kernel -> +33us; here it rides k_dft's occupancy shadow).

#define BB 16
#define X 16384
#define XP 16386
#define XPAD 16512   // 129*128; rows 16B-aligned, pad zeros
#define W 64
#define H 128
#define M 64
#define NB 4
#define NC 3

typedef __hip_bfloat16 bf16;
typedef __attribute__((ext_vector_type(8))) short short8;
typedef __attribute__((ext_vector_type(4))) float floatx4;

__device__ __forceinline__ float gelu_f(float x){
  float x3 = x * x * x;
  float y2 = 1.5957691216f * x + 0.0713548162f * x3;
  float e = __expf(y2);
  float th = 1.f - 2.f / (e + 1.f);
  return 0.5f * x * (1.f + th);
}
__device__ __forceinline__ float softplus_f(float v){
  return (v > 20.f) ? v : log1pf(expf(v));
}
__device__ __forceinline__ short f2bs(float f){   // fp32 -> bf16 bits (RNE)
  union { float f; unsigned u; } v; v.f = f;
  unsigned r = (v.u + 0x7FFFu + ((v.u >> 16) & 1u)) >> 16;
  return (short)r;
}
__device__ __forceinline__ float bs2f(short s){
  union { unsigned u; float f; } v; v.u = ((unsigned)(unsigned short)s) << 16;
  return v.f;
}
#define MFMA(a,b,c) __builtin_amdgcn_mfma_f32_16x16x32_bf16((a),(b),(c),0,0,0)

// ---------------- bases (coalesced writes) ----------------
__global__ __launch_bounds__(256) void k_basisT(short* __restrict__ basT16){
  int idx = blockIdx.x * 256 + threadIdx.x;
  if (idx >= 128 * XPAD) return;
  int mp = idx / XPAD, x = idx - mp * XPAD;
  float v = 0.f;
  if (x < XP){
    int m = mp >> 1;
    int tt = (int)(((long long)x * (long long)m) % XP);
    float ang = 6.283185307179586477f * (float)tt / (float)XP;
    float s, c; sincosf(ang, &s, &c);
    v = (mp & 1) ? s : c;
  }
  basT16[idx] = f2bs(v);
}
__global__ __launch_bounds__(256) void k_basisC(short* __restrict__ basC16){
  int idx = blockIdx.x * 256 + threadIdx.x;
  if (idx >= XPAD * 128) return;
  int x = idx >> 7, kp = idx & 127;
  float v = 0.f;
  if (x < XP){
    int m = kp >> 1;
    int tt = (int)(((long long)x * (long long)m) % XP);
    float ang = 6.283185307179586477f * (float)tt / (float)XP;
    float s, c; sincosf(ang, &s, &c);
    v = (kp & 1) ? -s : c;
  }
  basC16[idx] = f2bs(v);
}

__global__ __launch_bounds__(256) void k_decay(const float* __restrict__ log_decay,
                                               float* __restrict__ expz,
                                               float* __restrict__ phi){
  int idx = blockIdx.x * 256 + threadIdx.x;
  if (idx >= NB * W * M) return;
  float z = -softplus_f(log_decay[idx]);
  expz[idx] = expf(z);
  float p;
  if (fabsf(z) < 1e-6f) p = 1.0f + 0.5f * z + z * z * (1.0f / 6.0f);
  else                  p = expm1f(z) / z;
  phi[idx] = p;
}

// filt + tailB (post-negation basis at x=16384,16385; tailB[xi*128+mp])
__global__ void k_filt(float* __restrict__ filt, float* __restrict__ tailB){
  int t = threadIdx.x;
  if (t < M){
    float g = (float)t / 63.0f;
    float r2 = g * g + 1e-12f;
    float r4 = r2 * r2;
    float r8 = r4 * r4;
    filt[t] = expf(-2.0f * r8);
  }
  int xi = t >> 7, mp = t & 127;
  int m = mp >> 1;
  int tt = (int)(((long long)(16384 + xi) * m) % XP);
  float s, c;
  sincosf(6.283185307179586477f * (float)tt / (float)XP, &s, &c);
  tailB[xi * 128 + mp] = (mp & 1) ? -s : c;
}

// bf16 weights: ww16=aw*w_w, w116=g_w1, w1fc16=fc1_w, w0fc16=fc0_w (K 31->32)
__global__ __launch_bounds__(256) void k_prep(const float* __restrict__ w_w,
                                              const float* __restrict__ g_w1,
                                              const float* __restrict__ fc1_w,
                                              const float* __restrict__ fc0_w,
                                              const float* __restrict__ awr,
                                              short* __restrict__ ww16,
                                              short* __restrict__ w116,
                                              short* __restrict__ w1fc16,
                                              short* __restrict__ w0fc16){
  int idx = blockIdx.x * 256 + threadIdx.x;
  float aw = softplus_f(awr[0]);
  if (idx < 16384){ ww16[idx] = f2bs(aw * w_w[idx]); }
  else if (idx < 49152){ int i = idx - 16384; w116[i] = f2bs(g_w1[i]); }
  else if (idx < 57344){ int i = idx - 49152; w1fc16[i] = f2bs(fc1_w[i]); }
  else if (idx < 59392){
    int i = idx - 57344;
    int o = i >> 5, f = i & 31;
    w0fc16[i] = (f < 31) ? f2bs(fc0_w[o * 31 + f]) : (short)0;
  }
}

// ---------------- fc0 (MFMA): h16 + hX, pad zeros ----------------
__global__ __launch_bounds__(256) void k_fc0m(const float* __restrict__ xg,
                                              const float* __restrict__ gg,
                                              const short* __restrict__ w0fc16,
                                              const float* __restrict__ bg,
                                              short* __restrict__ h16,
                                              short* __restrict__ hX){
  __shared__ short xs16[128][40];
  __shared__ short xp[128][72];
  int b = blockIdx.y, bx = blockIdx.x, x0 = bx * 128, t = threadIdx.x;
  if (bx == 128){                       // pad rows: zero h16 & hX
    for (int i = t; i < 64 * 128; i += 256){
      int c = i >> 7, x = i & 127;
      h16[((size_t)b * 64 + c) * XPAD + x0 + x] = 0;
    }
    short8 z8 = (short8){0,0,0,0,0,0,0,0};
    for (int u = 0; u < 4; ++u){
      int idx = u * 256 + t;
      int x = idx >> 3, col = (idx & 7) * 8;
      *(short8*)&hX[((size_t)b * XPAD + x0 + x) * 64 + col] = z8;
    }
    return;
  }
  for (int i = t; i < 3840; i += 256){
    int x = i / 30, f = i - x * 30;
    xs16[x][f] = f2bs(xg[((size_t)b * X + x0 + x) * 30 + f]);
  }
  if (t < 128){ xs16[t][30] = f2bs(gg[(size_t)b * X + x0 + t]); xs16[t][31] = 0; }
  __syncthreads();
  int w = t >> 6, l = t & 63, q = l >> 4, ln = l & 15;
  floatx4 acc[4][2];
  #pragma unroll
  for (int mt = 0; mt < 4; ++mt)
    #pragma unroll
    for (int nt = 0; nt < 2; ++nt) acc[mt][nt] = (floatx4){0.f,0.f,0.f,0.f};
  #pragma unroll
  for (int mt = 0; mt < 4; ++mt){
    short8 av = *(const short8*)&w0fc16[(mt * 16 + ln) * 32 + q * 8];
    #pragma unroll
    for (int nt = 0; nt < 2; ++nt){
      short8 bv = *(const short8*)&xs16[w * 32 + nt * 16 + ln][q * 8];
      acc[mt][nt] = MFMA(av, bv, acc[mt][nt]);
    }
  }
  #pragma unroll
  for (int mt = 0; mt < 4; ++mt)
    #pragma unroll
    for (int r = 0; r < 4; ++r){
      int o = mt * 16 + q * 4 + r;
      float bias = bg[o];
      #pragma unroll
      for (int nt = 0; nt < 2; ++nt){
        int xl = w * 32 + nt * 16 + ln;
        short s = f2bs(acc[mt][nt][r] + bias);
        h16[((size_t)b * 64 + o) * XPAD + x0 + xl] = s;
        xp[xl][o] = s;
      }
    }
  __syncthreads();
  #pragma unroll
  for (int u = 0; u < 4; ++u){
    int idx = u * 256 + t;
    int x = idx >> 3, col = (idx & 7) * 8;
    *(short8*)&hX[((size_t)b * XPAD + x0 + x) * 64 + col] = *(const short8*)&xp[x][col];
  }
}

// ---------------- DFT (64 modes) with fused gmid, MFMA split-K, fp32 atomics ----------------
// chunks 0..127 (8 per wg); bx==15 epilogue adds the x=16384,16385 tail.
__global__ __launch_bounds__(256) void k_dft(const short* __restrict__ h16,
                                             const short* __restrict__ hX,
                                             const short* __restrict__ w116,
                                             const float* __restrict__ b1g,
                                             const short* __restrict__ basT16,
                                             const float* __restrict__ tailB,
                                             float* __restrict__ vhat,
                                             float* __restrict__ gmidhat, int blk){
  __shared__ __align__(16) char smem[52224];
  short (*srcT)[136] = (short(*)[136])smem;            // 64x136, persistent
  short (*hT)[72]    = (short(*)[72])(smem + 17408);   // 128x72, W1 phase
  short (*basS)[136] = (short(*)[136])(smem + 17408);  // 128x136, DFT phase
  int b = blockIdx.y, z = blockIdx.z, bx = blockIdx.x, t = threadIdx.x;
  int w = t >> 6, l = t & 63, q = l >> 4, ln = l & 15;
  const short* hbase = h16 + (size_t)b * 64 * XPAD;
  const short* hXb   = hX + (size_t)b * XPAD * 64;
  floatx4 acc[8];
  #pragma unroll
  for (int i = 0; i < 8; ++i) acc[i] = (floatx4){0.f,0.f,0.f,0.f};
  short8 aw1[2];
  float bias[4];
  if (z){
    #pragma unroll
    for (int ks = 0; ks < 2; ++ks)
      aw1[ks] = *(const short8*)&w116[((size_t)blk * H + (z-1)*64 + w*16 + ln) * 64 + ks*32 + q*8];
    #pragma unroll
    for (int r = 0; r < 4; ++r)
      bias[r] = b1g[blk * H + (z-1)*64 + w*16 + q*4 + r];
  }
  for (int ci = bx; ci < 128; ci += 16){
    int xc = ci * 128;
    __syncthreads();                           // prior-iter LDS reads done
    if (z == 0){
      #pragma unroll
      for (int u = 0; u < 4; ++u){
        int idx = u * 256 + t;
        int c = idx >> 4, col = (idx & 15) * 8;
        *(short8*)&srcT[c][col] = *(const short8*)&hbase[(size_t)c * XPAD + xc + col];
      }
    } else {
      #pragma unroll
      for (int u = 0; u < 4; ++u){             // hT[x][c] from hX rows (vector)
        int idx = u * 256 + t;
        int x = idx >> 3, col = (idx & 7) * 8;
        *(short8*)&hT[x][col] = *(const short8*)&hXb[(size_t)(xc + x) * 64 + col];
      }
    }
    __syncthreads();
    if (z){
      floatx4 a2[8];
      #pragma unroll
      for (int i = 0; i < 8; ++i) a2[i] = (floatx4){0.f,0.f,0.f,0.f};
      #pragma unroll
      for (int ks = 0; ks < 2; ++ks){
        #pragma unroll
        for (int nt = 0; nt < 8; ++nt){
          short8 bv = *(const short8*)&hT[nt*16 + ln][ks*32 + q*8];
          a2[nt] = MFMA(aw1[ks], bv, a2[nt]);
        }
      }
      #pragma unroll
      for (int nt = 0; nt < 8; ++nt){
        #pragma unroll
        for (int r = 0; r < 4; ++r){
          int o = w*16 + q*4 + r;
          float vv = gelu_f(a2[nt][r] + bias[r]);
          srcT[o][nt*16 + ln] = f2bs(vv);      // gx < XP always for ci<128
        }
      }
    }
    __syncthreads();                           // hT reads done; srcT visible
    #pragma unroll
    for (int u = 0; u < 8; ++u){
      int idx = u * 256 + t;
      int mp = idx >> 4, col = (idx & 15) * 8;
      *(short8*)&basS[mp][col] = *(const short8*)&basT16[(size_t)mp * XPAD + xc + col];
    }
    __syncthreads();
    #pragma unroll
    for (int ks = 0; ks < 4; ++ks){
      short8 av = *(const short8*)&srcT[w*16 + ln][ks*32 + q*8];
      #pragma unroll
      for (int nt = 0; nt < 8; ++nt){
        short8 bv = *(const short8*)&basS[nt*16 + ln][ks*32 + q*8];
        acc[nt] = MFMA(av, bv, acc[nt]);
      }
    }
  }
  #pragma unroll
  for (int nt = 0; nt < 8; ++nt)
    #pragma unroll
    for (int r = 0; r < 4; ++r){
      int mp = nt*16 + ln;
      int c  = w*16 + q*4 + r;
      float v = acc[nt][r];
      if (mp & 1) v = -v;                      // im = -sum(src*sin)
      if (z == 0) atomicAdd(&vhat[((size_t)b * W + c) * 128 + mp], v);
      else atomicAdd(&gmidhat[((size_t)b * H + (z-1)*64 + c) * 128 + mp], v);
    }
  // ---- tail epilogue (x=16384,16385), bx==15 only (uniform branch) ----
  if (bx == 15){
    __syncthreads();                           // MFMA LDS reads complete
    float* tb = (float*)smem;                  // 256 floats
    float* gm = tb + 256;                      // 128 floats (z>=1)
    tb[t] = tailB[t];
    __syncthreads();
    if (z == 0){
      for (int i = t; i < 8192; i += 256){
        int c = i >> 7, mp = i & 127;
        float h0 = bs2f(hbase[(size_t)c * XPAD + 16384]);
        float h1 = bs2f(hbase[(size_t)c * XPAD + 16385]);
        atomicAdd(&vhat[((size_t)b * W + c) * 128 + mp],
                  h0 * tb[mp] + h1 * tb[128 + mp]);
      }
    } else {
      if (t < 128){
        int j = t >> 1, xi = t & 1;
        int o2 = (z - 1) * 64 + j;
        float a2 = b1g[blk * H + o2];
        const short* w1r = w116 + ((size_t)blk * H + o2) * 64;
        for (int c = 0; c < 64; ++c)
          a2 = fmaf(bs2f(w1r[c]), bs2f(hbase[(size_t)c * XPAD + 16384 + xi]), a2);
        gm[t] = gelu_f(a2);                    // gm[j*2+xi]
      }
      __syncthreads();
      for (int i = t; i < 8192; i += 256){
        int j = i >> 7, mp = i & 127;
        float v = gm[j * 2 + 0] * tb[mp] + gm[j * 2 + 1] * tb[128 + mp];
        atomicAdd(&gmidhat[((size_t)b * H + (z-1)*64 + j) * 128 + mp], v);
      }
    }
  }
}

// ---------------- ghat = ag*(W2 @ gmidhat) + ag*b2*XP at m=0 ----------------
__global__ __launch_bounds__(256) void k_ghat(const float* __restrict__ gmidhat,
                                              const float* __restrict__ w2g,
                                              const float* __restrict__ b2g,
                                              const float* __restrict__ agr,
                                              float* __restrict__ ghat, int blk){
  __shared__ float w2s[64][133];
  int b = blockIdx.x, zg = blockIdx.y, t = threadIdx.x;
  float ag = softplus_f(agr[0]);
  for (int i = t; i < 8192; i += 256) w2s[i >> 7][i & 127] = w2g[(size_t)blk * 8192 + i];
  __syncthreads();
  int i = t & 63, ms = t >> 6;
  int mp0 = zg * 16 + ms * 4;
  for (int j = 0; j < 4; ++j){
    int mp = mp0 + j;
    float acc = 0.f;
    for (int c2 = 0; c2 < H; ++c2)
      acc = fmaf(w2s[i][c2], gmidhat[((size_t)b * H + c2) * 128 + mp], acc);
    if (mp == 0) acc += (float)XP * b2g[blk * W + i];
    ghat[((size_t)b * W + i) * 128 + mp] = ag * acc;
  }
}

// ---------------- out_m (fp32 VALU; bf16 output) ----------------
__global__ __launch_bounds__(256) void k_outm(const float* __restrict__ vhat,
                       const float* __restrict__ ghat,
                       const float* __restrict__ mix_re, const float* __restrict__ mix_im,
                       const float* __restrict__ expz, const float* __restrict__ phi,
                       const float* __restrict__ filt, short* __restrict__ outm16, int blk){
  int b = blockIdx.y, t = threadIdx.x;
  int m = t & 63, os = t >> 6;
  int o = blockIdx.x * 4 + os;
  const float* mre = mix_re + (size_t)blk * W * W * M + (size_t)o * M + m;
  const float* mim = mix_im + (size_t)blk * W * W * M + (size_t)o * M + m;
  float gr = 0.f, gi = 0.f;
  for (int i = 0; i < W; ++i){
    float gre = ghat[((size_t)b * W + i) * 128 + 2 * m];
    float gim = ghat[((size_t)b * W + i) * 128 + 2 * m + 1];
    float xr = mre[(size_t)i * W * M];
    float xi = mim[(size_t)i * W * M];
    gr = fmaf(gre, xr, gr); gr = fmaf(-gim, xi, gr);
    gi = fmaf(gre, xi, gi); gi = fmaf( gim, xr, gi);
  }
  int om = blk * W * M + o * M + m;
  float ez = expz[om], ph = phi[om], fl = filt[m];
  float vr = vhat[((size_t)b * W + o) * 128 + 2 * m];
  float vi = vhat[((size_t)b * W + o) * 128 + 2 * m + 1];
  float outr = fmaf(ez, vr, ph * fl * gr);
  float outi = fmaf(ez, vi, ph * fl * gi);
  float sc = ((m == 0) ? 1.0f : 2.0f) / (float)XP;
  outm16[((size_t)b * W + o) * 128 + 2 * m]     = f2bs(outr * sc);
  outm16[((size_t)b * W + o) * 128 + 2 * m + 1] = f2bs(outi * sc);
}

// ---------------- update: h = act(iDFT(out_m) + aw*(W h + b)); split-K ETD ----------------
// LDS 36864 (granule-exact) -> 4 wg/CU. A: hT/basH/xp; B: wwS/omH0; C: omH1.
__global__ __launch_bounds__(256) void k_update(short* __restrict__ h16,
                                                short* __restrict__ hX,
                                                const short* __restrict__ outm16,
                                                const short* __restrict__ basC16,
                                                const short* __restrict__ ww16,
                                                const float* __restrict__ wbg,
                                                const float* __restrict__ awr, int blk){
  __shared__ __align__(16) char smem[36864];
  short (*hT)[72]   = (short(*)[72])smem;              // A: 128x72 = 18432
  short (*basH)[72] = (short(*)[72])smem;              // A reuse
  short (*xp)[72]   = (short(*)[72])smem;              // A reuse (epilogue)
  short (*wwS)[72]  = (short(*)[72])(smem + 18432);    // B: 64x72 = 9216
  short (*omH0)[72] = (short(*)[72])(smem + 18432);    // B reuse
  short (*omH1)[72] = (short(*)[72])(smem + 27648);    // C: 64x72 = 9216
  int b = blockIdx.y, ci = blockIdx.x, x0 = ci * 128, t = threadIdx.x;
  int w = t >> 6, l = t & 63, q = l >> 4, ln = l & 15;
  float aw = softplus_f(awr[0]);
  const short* hXb = hX + (size_t)b * XPAD * 64;
  #pragma unroll
  for (int u = 0; u < 4; ++u){                 // hT from hX rows (vector)
    int idx = u * 256 + t;
    int x = idx >> 3, col = (idx & 7) * 8;
    *(short8*)&hT[x][col] = *(const short8*)&hXb[(size_t)(x0 + x) * 64 + col];
  }
  #pragma unroll
  for (int u = 0; u < 2; ++u){
    int idx = u * 256 + t;
    int o = idx >> 3, col = (idx & 7) * 8;
    *(short8*)&wwS[o][col] = *(const short8*)&ww16[((size_t)blk * W + o) * 64 + col];
  }
  __syncthreads();
  floatx4 acc[2][4];
  #pragma unroll
  for (int mt = 0; mt < 2; ++mt)
    #pragma unroll
    for (int nt = 0; nt < 4; ++nt) acc[mt][nt] = (floatx4){0.f,0.f,0.f,0.f};
  #pragma unroll
  for (int ks = 0; ks < 2; ++ks){              // aw*W@h: K=64
    short8 a0 = *(const short8*)&hT[(w*2+0)*16 + ln][ks*32 + q*8];
    short8 a1 = *(const short8*)&hT[(w*2+1)*16 + ln][ks*32 + q*8];
    #pragma unroll
    for (int nt = 0; nt < 4; ++nt){
      short8 bv = *(const short8*)&wwS[nt*16 + ln][ks*32 + q*8];
      acc[0][nt] = MFMA(a0, bv, acc[0][nt]);
      acc[1][nt] = MFMA(a1, bv, acc[1][nt]);
    }
  }
  __syncthreads();                             // A,B reads done
  #pragma unroll
  for (int u = 0; u < 4; ++u){                 // basC half0 -> A
    int idx = u * 256 + t;
    int x = idx >> 3, col = (idx & 7) * 8;
    *(short8*)&basH[x][col] = *(const short8*)&basC16[(size_t)(x0 + x) * 128 + col];
  }
  #pragma unroll
  for (int u = 0; u < 2; ++u){                 // omS halves -> B, C
    int idx = u * 256 + t;
    int o = idx >> 3, col = (idx & 7) * 8;
    *(short8*)&omH0[o][col] = *(const short8*)&outm16[((size_t)b * W + o) * 128 + col];
    *(short8*)&omH1[o][col] = *(const short8*)&outm16[((size_t)b * W + o) * 128 + 64 + col];
  }
  __syncthreads();
  #pragma unroll
  for (int ks = 0; ks < 2; ++ks){              // etd kp 0..63
    short8 a0 = *(const short8*)&basH[(w*2+0)*16 + ln][ks*32 + q*8];
    short8 a1 = *(const short8*)&basH[(w*2+1)*16 + ln][ks*32 + q*8];
    #pragma unroll
    for (int nt = 0; nt < 4; ++nt){
      short8 bv = *(const short8*)&omH0[nt*16 + ln][ks*32 + q*8];
      acc[0][nt] = MFMA(a0, bv, acc[0][nt]);
      acc[1][nt] = MFMA(a1, bv, acc[1][nt]);
    }
  }
  __syncthreads();                             // A half0 reads done
  #pragma unroll
  for (int u = 0; u < 4; ++u){                 // basC half1 -> A
    int idx = u * 256 + t;
    int x = idx >> 3, col = (idx & 7) * 8;
    *(short8*)&basH[x][col] = *(const short8*)&basC16[(size_t)(x0 + x) * 128 + 64 + col];
  }
  __syncthreads();
  #pragma unroll
  for (int ks = 0; ks < 2; ++ks){              // etd kp 64..127
    short8 a0 = *(const short8*)&basH[(w*2+0)*16 + ln][ks*32 + q*8];
    short8 a1 = *(const short8*)&basH[(w*2+1)*16 + ln][ks*32 + q*8];
    #pragma unroll
    for (int nt = 0; nt < 4; ++nt){
      short8 bv = *(const short8*)&omH1[nt*16 + ln][ks*32 + q*8];
      acc[0][nt] = MFMA(a0, bv, acc[0][nt]);
      acc[1][nt] = MFMA(a1, bv, acc[1][nt]);
    }
  }
  // epilogue: compute bf16 outputs, write h16 directly
  short sreg[2][4][4];
  #pragma unroll
  for (int mt = 0; mt < 2; ++mt)
    #pragma unroll
    for (int nt = 0; nt < 4; ++nt){
      int o = nt*16 + ln;
      int xbase = x0 + (w*2+mt)*16 + q*4;
      float wbv = aw * wbg[blk * W + o];
      short* hp = &h16[((size_t)b * 64 + o) * XPAD + xbase];
      #pragma unroll
      for (int r = 0; r < 4; ++r){
        float u = acc[mt][nt][r] + wbv;
        if (blk != NB - 1) u = gelu_f(u);
        sreg[mt][nt][r] = f2bs(u);
      }
      if (xbase + 3 < XP){
        *(short4*)hp = *(short4*)&sreg[mt][nt][0];
      } else {
        #pragma unroll
        for (int r = 0; r < 4; ++r)
          if (xbase + r < XP) hp[r] = sreg[mt][nt][r];
      }
    }
  __syncthreads();                             // A/C reads done
  #pragma unroll
  for (int mt = 0; mt < 2; ++mt)
    #pragma unroll
    for (int nt = 0; nt < 4; ++nt){
      int o = nt*16 + ln;
      int xl = (w*2+mt)*16 + q*4;
      #pragma unroll
      for (int r = 0; r < 4; ++r) xp[xl + r][o] = sreg[mt][nt][r];
    }
  __syncthreads();
  #pragma unroll
  for (int u = 0; u < 4; ++u){
    int idx = u * 256 + t;
    int x = idx >> 3, col = (idx & 7) * 8;
    if (x0 + x < XP)
      *(short8*)&hX[((size_t)b * XPAD + x0 + x) * 64 + col] = *(const short8*)&xp[x][col];
  }
}

// ---------------- fc12: MFMA fc1 + VALU fc2 -> out (fp32) ----------------
__global__ __launch_bounds__(256) void k_fc12(const short* __restrict__ hX,
                                              const short* __restrict__ w1fc16,
                                              const float* __restrict__ b1,
                                              const float* __restrict__ w2,
                                              const float* __restrict__ b2,
                                              float* __restrict__ out){
  __shared__ short hT[128][72];
  __shared__ short gT[128][136];
  __shared__ float w2s[NC][132];
  __shared__ float red[2][128][NC];
  int b = blockIdx.y, x0 = blockIdx.x * 128, t = threadIdx.x;
  int w = t >> 6, l = t & 63, q = l >> 4, ln = l & 15;
  const short* hXb = hX + (size_t)b * XPAD * 64;
  #pragma unroll
  for (int u = 0; u < 4; ++u){
    int idx = u * 256 + t;
    int x = idx >> 3, col = (idx & 7) * 8;
    *(short8*)&hT[x][col] = *(const short8*)&hXb[(size_t)(x0 + x) * 64 + col];
  }
  for (int i = t; i < NC * H; i += 256) w2s[i / H][i % H] = w2[i];
  __syncthreads();
  floatx4 acc[2][8];
  #pragma unroll
  for (int mt = 0; mt < 2; ++mt)
    #pragma unroll
    for (int nt = 0; nt < 8; ++nt) acc[mt][nt] = (floatx4){0.f,0.f,0.f,0.f};
  #pragma unroll
  for (int ks = 0; ks < 2; ++ks){
    short8 a0 = *(const short8*)&w1fc16[(size_t)((w*2+0)*16 + ln) * 64 + ks*32 + q*8];
    short8 a1 = *(const short8*)&w1fc16[(size_t)((w*2+1)*16 + ln) * 64 + ks*32 + q*8];
    #pragma unroll
    for (int nt = 0; nt < 8; ++nt){
      short8 bv = *(const short8*)&hT[nt*16 + ln][ks*32 + q*8];
      acc[0][nt] = MFMA(a0, bv, acc[0][nt]);
      acc[1][nt] = MFMA(a1, bv, acc[1][nt]);
    }
  }
  #pragma unroll
  for (int mt = 0; mt < 2; ++mt){
    float bvv[4];
    #pragma unroll
    for (int r = 0; r < 4; ++r) bvv[r] = b1[(w*2+mt)*16 + q*4 + r];
    #pragma unroll
    for (int nt = 0; nt < 8; ++nt){
      int x = nt*16 + ln;
      #pragma unroll
      for (int r = 0; r < 4; ++r)
        gT[x][(w*2+mt)*16 + q*4 + r] = f2bs(gelu_f(acc[mt][nt][r] + bvv[r]));
    }
  }
  __syncthreads();
  int x = t & 127, half = t >> 7;
  float a3[NC] = {0.f, 0.f, 0.f};
  for (int og = 0; og < 8; ++og){
    int o0 = half * 64 + og * 8;
    short8 gv = *(const short8*)&gT[x][o0];
    #pragma unroll
    for (int j = 0; j < 8; ++j){
      float gf = bs2f(gv[j]);
      #pragma unroll
      for (int n = 0; n < NC; ++n) a3[n] = fmaf(gf, w2s[n][o0 + j], a3[n]);
    }
  }
  #pragma unroll
  for (int n = 0; n < NC; ++n) red[half][x][n] = a3[n];
  __syncthreads();
  if (half == 0){
    #pragma unroll
    for (int n = 0; n < NC; ++n)
      out[((size_t)b * X + x0 + x) * NC + n] = red[0][x][n] + red[1][x][n] + b2[n];
  }
}

extern "C" void kernel_launch(void* const* d_in, const int* in_sizes, int n_in,
                              void* d_out, int out_size, void* d_ws, size_t ws_size,
                              hipStream_t stream){
  (void)in_sizes; (void)n_in; (void)out_size; (void)ws_size;
  const float* x        = (const float*)d_in[0];
  const float* grid     = (const float*)d_in[1];
  const float* fc0_w    = (const float*)d_in[2];
  const float* fc0_b    = (const float*)d_in[3];
  const float* fc1_w    = (const float*)d_in[4];
  const float* fc1_b    = (const float*)d_in[5];
  const float* fc2_w    = (const float*)d_in[6];
  const float* fc2_b    = (const float*)d_in[7];
  const float* g_w1     = (const float*)d_in[8];
  const float* g_b1     = (const float*)d_in[9];
  const float* g_w2     = (const float*)d_in[10];
  const float* g_b2     = (const float*)d_in[11];
  const float* w_w      = (const float*)d_in[12];
  const float* w_b      = (const float*)d_in[13];
  const float* log_dec  = (const float*)d_in[14];
  const float* mix_re   = (const float*)d_in[15];
  const float* mix_im   = (const float*)d_in[16];
  const float* a_w      = (const float*)d_in[17];
  const float* a_g      = (const float*)d_in[18];
  float* out = (float*)d_out;

  // workspace carve (~78 MB, 16B aligned)
  short* basC16 = (short*)d_ws;                         // XPAD*128
  short* basT16 = basC16 + (size_t)XPAD * 128;          // 128*XPAD
  short* h16    = basT16 + (size_t)128 * XPAD;          // BB*64*XPAD
  short* hX     = h16 + (size_t)BB * 64 * XPAD;         // BB*XPAD*64
  float* vhat   = (float*)(hX + (size_t)BB * XPAD * 64);
  float* gmidhat= vhat + (size_t)BB * W * 128;
  float* ghat   = gmidhat + (size_t)BB * H * 128;
  float* expz   = ghat + (size_t)BB * W * 128;
  float* phi    = expz + NB * W * M;
  float* filt   = phi + NB * W * M;
  float* tailB  = filt + 64;                            // 256 floats
  short* outm16 = (short*)(tailB + 256);
  short* ww16   = outm16 + (size_t)BB * W * 128;
  short* w116   = ww16 + NB * W * W;
  short* w1fc16 = w116 + NB * H * W;
  short* w0fc16 = w1fc16 + H * W;

  k_basisT<<<dim3((128 * XPAD + 255) / 256), 256, 0, stream>>>(basT16);
  k_basisC<<<dim3((XPAD * 128 + 255) / 256), 256, 0, stream>>>(basC16);
  k_decay<<<dim3((NB * W * M + 255) / 256), 256, 0, stream>>>(log_dec, expz, phi);
  k_filt<<<1, 256, 0, stream>>>(filt, tailB);
  k_prep<<<dim3(232), 256, 0, stream>>>(w_w, g_w1, fc1_w, fc0_w, a_w, ww16, w116, w1fc16, w0fc16);
  k_fc0m<<<dim3(129, BB), 256, 0, stream>>>(x, grid, w0fc16, fc0_b, h16, hX);

  for (int blk = 0; blk < NB; ++blk){
    hipMemsetAsync(vhat, 0, (size_t)(BB * W * 128 + BB * H * 128) * sizeof(float), stream);
    k_dft<<<dim3(16, BB, 3), 256, 0, stream>>>(h16, hX, w116, g_b1, basT16, tailB, vhat, gmidhat, blk);
    k_ghat<<<dim3(BB, 8), 256, 0, stream>>>(gmidhat, g_w2, g_b2, a_g, ghat, blk);
    k_outm<<<dim3(16, BB), 256, 0, stream>>>(vhat, ghat, mix_re, mix_im, expz, phi, filt, outm16, blk);
    k_update<<<dim3(XPAD / 128, BB), 256, 0, stream>>>(h16, hX, outm16, basC16, ww16, w_b, a_w, blk);
  }
  k_fc12<<<dim3(X / 128, BB), 256, 0, stream>>>(hX, w1fc16, fc1_b, fc2_w, fc2_b, out);
}

// Round 18
// 605.760 us; speedup vs baseline: 1.0853x; 1.0853x over previous
//
#include <hip/hip_runtime.h>
#include <hip/hip_bf16.h>

// SGNO1d: B=16, X=16384, Xp=16386, W=64, H=128, M=64, NB=4.
// MFMA bf16 pipeline. h in two layouts: h16[b][c][XPAD] + hX[b][x][64].
// R18 = R14 hot path EXACTLY (k_dft stride136/52224B/3wg/CU, 9-pass chunk
// walk incl. chunk 128; both tail-folding attempts R16/R17 lost to it) +
// non-dft cleanups: k_ghat regrid (BB,32) 1mp/thread; self-cleaning vhat/
// gmidhat (3 of 4 memsets removed); basis & prep kernel fusion; gelu via
// exact sigmoid identity (12->8 VALU).

#define BB 16
#define X 16384
#define XP 16386
#define XPAD 16512   // 129*128; rows 16B-aligned, pad zeros
#define W 64
#define H 128
#define M 64
#define NB 4
#define NC 3

typedef __hip_bfloat16 bf16;
typedef __attribute__((ext_vector_type(8))) short short8;
typedef __attribute__((ext_vector_type(4))) float floatx4;

__device__ __forceinline__ float gelu_f(float x){
  // gelu(x) = x * sigmoid(1.5957691216 x + 0.0713548162 x^3)  (== tanh form)
  float x2 = x * x;
  float inner = fmaf(0.0713548162f, x2, 1.5957691216f);
  float e = __expf(-x * inner);
  return x / (1.f + e);
}
__device__ __forceinline__ float softplus_f(float v){
  return (v > 20.f) ? v : log1pf(expf(v));
}
__device__ __forceinline__ short f2bs(float f){   // fp32 -> bf16 bits (RNE)
  union { float f; unsigned u; } v; v.f = f;
  unsigned r = (v.u + 0x7FFFu + ((v.u >> 16) & 1u)) >> 16;
  return (short)r;
}
__device__ __forceinline__ float bs2f(short s){
  union { unsigned u; float f; } v; v.u = ((unsigned)(unsigned short)s) << 16;
  return v.f;
}
#define MFMA(a,b,c) __builtin_amdgcn_mfma_f32_16x16x32_bf16((a),(b),(c),0,0,0)

// ---------------- bases (fused, coalesced writes) ----------------
__global__ __launch_bounds__(256) void k_basis2(short* __restrict__ basT16,
                                                short* __restrict__ basC16){
  int idx = blockIdx.x * 256 + threadIdx.x;
  const int N1 = 128 * XPAD;
  if (idx < N1){
    int mp = idx / XPAD, x = idx - mp * XPAD;
    float v = 0.f;
    if (x < XP){
      int m = mp >> 1;
      int tt = (int)(((long long)x * (long long)m) % XP);
      float ang = 6.283185307179586477f * (float)tt / (float)XP;
      float s, c; sincosf(ang, &s, &c);
      v = (mp & 1) ? s : c;
    }
    basT16[idx] = f2bs(v);
  } else if (idx < 2 * N1){
    int i = idx - N1;
    int x = i >> 7, kp = i & 127;
    float v = 0.f;
    if (x < XP){
      int m = kp >> 1;
      int tt = (int)(((long long)x * (long long)m) % XP);
      float ang = 6.283185307179586477f * (float)tt / (float)XP;
      float s, c; sincosf(ang, &s, &c);
      v = (kp & 1) ? -s : c;
    }
    basC16[i] = f2bs(v);
  }
}

// ---------------- fused prep: decay + filt + bf16 weight copies ----------------
__global__ __launch_bounds__(256) void k_prep2(const float* __restrict__ log_decay,
                                               const float* __restrict__ w_w,
                                               const float* __restrict__ g_w1,
                                               const float* __restrict__ fc1_w,
                                               const float* __restrict__ fc0_w,
                                               const float* __restrict__ awr,
                                               float* __restrict__ expz,
                                               float* __restrict__ phi,
                                               float* __restrict__ filt,
                                               short* __restrict__ ww16,
                                               short* __restrict__ w116,
                                               short* __restrict__ w1fc16,
                                               short* __restrict__ w0fc16){
  int idx = blockIdx.x * 256 + threadIdx.x;
  if (idx < 16384){                       // decay (NB*W*M)
    float z = -softplus_f(log_decay[idx]);
    expz[idx] = expf(z);
    float p;
    if (fabsf(z) < 1e-6f) p = 1.0f + 0.5f * z + z * z * (1.0f / 6.0f);
    else                  p = expm1f(z) / z;
    phi[idx] = p;
    return;
  }
  int j = idx - 16384;
  if (j < 64){                            // filt
    float g = (float)j / 63.0f;
    float r2 = g * g + 1e-12f;
    float r4 = r2 * r2;
    float r8 = r4 * r4;
    filt[j] = expf(-2.0f * r8);
    return;
  }
  j -= 64;
  float aw = softplus_f(awr[0]);
  if (j < 16384){ ww16[j] = f2bs(aw * w_w[j]); }
  else if (j < 49152){ int i = j - 16384; w116[i] = f2bs(g_w1[i]); }
  else if (j < 57344){ int i = j - 49152; w1fc16[i] = f2bs(fc1_w[i]); }
  else if (j < 59392){
    int i = j - 57344;
    int o = i >> 5, f = i & 31;
    w0fc16[i] = (f < 31) ? f2bs(fc0_w[o * 31 + f]) : (short)0;
  }
}

// ---------------- fc0 (MFMA): h16 + hX, pad zeros ----------------
__global__ __launch_bounds__(256) void k_fc0m(const float* __restrict__ xg,
                                              const float* __restrict__ gg,
                                              const short* __restrict__ w0fc16,
                                              const float* __restrict__ bg,
                                              short* __restrict__ h16,
                                              short* __restrict__ hX){
  __shared__ short xs16[128][40];
  __shared__ short xp[128][72];
  int b = blockIdx.y, bx = blockIdx.x, x0 = bx * 128, t = threadIdx.x;
  if (bx == 128){                       // pad rows: zero h16 & hX
    for (int i = t; i < 64 * 128; i += 256){
      int c = i >> 7, x = i & 127;
      h16[((size_t)b * 64 + c) * XPAD + x0 + x] = 0;
    }
    short8 z8 = (short8){0,0,0,0,0,0,0,0};
    for (int u = 0; u < 4; ++u){
      int idx = u * 256 + t;
      int x = idx >> 3, col = (idx & 7) * 8;
      *(short8*)&hX[((size_t)b * XPAD + x0 + x) * 64 + col] = z8;
    }
    return;
  }
  for (int i = t; i < 3840; i += 256){
    int x = i / 30, f = i - x * 30;
    xs16[x][f] = f2bs(xg[((size_t)b * X + x0 + x) * 30 + f]);
  }
  if (t < 128){ xs16[t][30] = f2bs(gg[(size_t)b * X + x0 + t]); xs16[t][31] = 0; }
  __syncthreads();
  int w = t >> 6, l = t & 63, q = l >> 4, ln = l & 15;
  floatx4 acc[4][2];
  #pragma unroll
  for (int mt = 0; mt < 4; ++mt)
    #pragma unroll
    for (int nt = 0; nt < 2; ++nt) acc[mt][nt] = (floatx4){0.f,0.f,0.f,0.f};
  #pragma unroll
  for (int mt = 0; mt < 4; ++mt){
    short8 av = *(const short8*)&w0fc16[(mt * 16 + ln) * 32 + q * 8];
    #pragma unroll
    for (int nt = 0; nt < 2; ++nt){
      short8 bv = *(const short8*)&xs16[w * 32 + nt * 16 + ln][q * 8];
      acc[mt][nt] = MFMA(av, bv, acc[mt][nt]);
    }
  }
  #pragma unroll
  for (int mt = 0; mt < 4; ++mt)
    #pragma unroll
    for (int r = 0; r < 4; ++r){
      int o = mt * 16 + q * 4 + r;
      float bias = bg[o];
      #pragma unroll
      for (int nt = 0; nt < 2; ++nt){
        int xl = w * 32 + nt * 16 + ln;
        short s = f2bs(acc[mt][nt][r] + bias);
        h16[((size_t)b * 64 + o) * XPAD + x0 + xl] = s;
        xp[xl][o] = s;
      }
    }
  __syncthreads();
  #pragma unroll
  for (int u = 0; u < 4; ++u){
    int idx = u * 256 + t;
    int x = idx >> 3, col = (idx & 7) * 8;
    *(short8*)&hX[((size_t)b * XPAD + x0 + x) * 64 + col] = *(const short8*)&xp[x][col];
  }
}

// ---------------- DFT (64 modes) with fused gmid, MFMA split-K, fp32 atomics ----------------
// R14-exact: stride 136, LDS 52224 (3 wg/CU), grid (16, BB, 3), ci < 129.
__global__ __launch_bounds__(256) void k_dft(const short* __restrict__ h16,
                                             const short* __restrict__ hX,
                                             const short* __restrict__ w116,
                                             const float* __restrict__ b1g,
                                             const short* __restrict__ basT16,
                                             float* __restrict__ vhat,
                                             float* __restrict__ gmidhat, int blk){
  __shared__ __align__(16) char smem[52224];
  short (*srcT)[136] = (short(*)[136])smem;            // 64x136, persistent
  short (*hT)[72]    = (short(*)[72])(smem + 17408);   // 128x72, W1 phase
  short (*basS)[136] = (short(*)[136])(smem + 17408);  // 128x136, DFT phase
  int b = blockIdx.y, z = blockIdx.z, bx = blockIdx.x, t = threadIdx.x;
  int w = t >> 6, l = t & 63, q = l >> 4, ln = l & 15;
  const short* hbase = h16 + (size_t)b * 64 * XPAD;
  const short* hXb   = hX + (size_t)b * XPAD * 64;
  floatx4 acc[8];
  #pragma unroll
  for (int i = 0; i < 8; ++i) acc[i] = (floatx4){0.f,0.f,0.f,0.f};
  short8 aw1[2];
  float bias[4];
  if (z){
    #pragma unroll
    for (int ks = 0; ks < 2; ++ks)
      aw1[ks] = *(const short8*)&w116[((size_t)blk * H + (z-1)*64 + w*16 + ln) * 64 + ks*32 + q*8];
    #pragma unroll
    for (int r = 0; r < 4; ++r)
      bias[r] = b1g[blk * H + (z-1)*64 + w*16 + q*4 + r];
  }
  for (int ci = bx; ci < 129; ci += 16){
    int xc = ci * 128;
    __syncthreads();                           // prior-iter LDS reads done
    if (z == 0){
      #pragma unroll
      for (int u = 0; u < 4; ++u){
        int idx = u * 256 + t;
        int c = idx >> 4, col = (idx & 15) * 8;
        *(short8*)&srcT[c][col] = *(const short8*)&hbase[(size_t)c * XPAD + xc + col];
      }
    } else {
      #pragma unroll
      for (int u = 0; u < 4; ++u){             // hT[x][c] from hX rows (vector)
        int idx = u * 256 + t;
        int x = idx >> 3, col = (idx & 7) * 8;
        *(short8*)&hT[x][col] = *(const short8*)&hXb[(size_t)(xc + x) * 64 + col];
      }
    }
    __syncthreads();
    if (z){
      floatx4 a2[8];
      #pragma unroll
      for (int i = 0; i < 8; ++i) a2[i] = (floatx4){0.f,0.f,0.f,0.f};
      #pragma unroll
      for (int ks = 0; ks < 2; ++ks){
        #pragma unroll
        for (int nt = 0; nt < 8; ++nt){
          short8 bv = *(const short8*)&hT[nt*16 + ln][ks*32 + q*8];
          a2[nt] = MFMA(aw1[ks], bv, a2[nt]);
        }
      }
      #pragma unroll
      for (int nt = 0; nt < 8; ++nt){
        int gx = xc + nt*16 + ln;
        #pragma unroll
        for (int r = 0; r < 4; ++r){
          int o = w*16 + q*4 + r;
          float vv = gelu_f(a2[nt][r] + bias[r]);
          srcT[o][nt*16 + ln] = (gx < XP) ? f2bs(vv) : (short)0;
        }
      }
    }
    __syncthreads();                           // hT reads done; srcT visible
    #pragma unroll
    for (int u = 0; u < 8; ++u){
      int idx = u * 256 + t;
      int mp = idx >> 4, col = (idx & 15) * 8;
      *(short8*)&basS[mp][col] = *(const short8*)&basT16[(size_t)mp * XPAD + xc + col];
    }
    __syncthreads();
    #pragma unroll
    for (int ks = 0; ks < 4; ++ks){
      short8 av = *(const short8*)&srcT[w*16 + ln][ks*32 + q*8];
      #pragma unroll
      for (int nt = 0; nt < 8; ++nt){
        short8 bv = *(const short8*)&basS[nt*16 + ln][ks*32 + q*8];
        acc[nt] = MFMA(av, bv, acc[nt]);
      }
    }
  }
  #pragma unroll
  for (int nt = 0; nt < 8; ++nt)
    #pragma unroll
    for (int r = 0; r < 4; ++r){
      int mp = nt*16 + ln;
      int c  = w*16 + q*4 + r;
      float v = acc[nt][r];
      if (mp & 1) v = -v;                      // im = -sum(src*sin)
      if (z == 0) atomicAdd(&vhat[((size_t)b * W + c) * 128 + mp], v);
      else atomicAdd(&gmidhat[((size_t)b * H + (z-1)*64 + c) * 128 + mp], v);
    }
}

// ---------------- ghat = ag*(W2 @ gmidhat) + ag*b2*XP at m=0 ----------------
// grid (BB, 32): 1 mp per thread (4x parallelism vs R14); zeroes gmidhat after.
__global__ __launch_bounds__(256) void k_ghat(float* __restrict__ gmidhat,
                                              const float* __restrict__ w2g,
                                              const float* __restrict__ b2g,
                                              const float* __restrict__ agr,
                                              float* __restrict__ ghat, int blk){
  __shared__ float w2s[64][133];
  int b = blockIdx.x, zg = blockIdx.y, t = threadIdx.x;
  float ag = softplus_f(agr[0]);
  for (int i = t; i < 8192; i += 256) w2s[i >> 7][i & 127] = w2g[(size_t)blk * 8192 + i];
  __syncthreads();
  int i = t & 63, ms = t >> 6;
  int mp = zg * 4 + ms;
  float acc = 0.f;
  for (int c2 = 0; c2 < H; ++c2)
    acc = fmaf(w2s[i][c2], gmidhat[((size_t)b * H + c2) * 128 + mp], acc);
  if (mp == 0) acc += (float)XP * b2g[blk * W + i];
  ghat[((size_t)b * W + i) * 128 + mp] = ag * acc;
  __syncthreads();                             // all reads of gmidhat done
  for (int u = t; u < 512; u += 256){          // zero slice for next blk
    int c2 = u >> 2, j = u & 3;
    gmidhat[((size_t)b * H + c2) * 128 + zg * 4 + j] = 0.f;
  }
}

// ---------------- out_m (fp32 VALU; bf16 output); zeroes vhat after read ----------------
__global__ __launch_bounds__(256) void k_outm(float* __restrict__ vhat,
                       const float* __restrict__ ghat,
                       const float* __restrict__ mix_re, const float* __restrict__ mix_im,
                       const float* __restrict__ expz, const float* __restrict__ phi,
                       const float* __restrict__ filt, short* __restrict__ outm16, int blk){
  int b = blockIdx.y, t = threadIdx.x;
  int m = t & 63, os = t >> 6;
  int o = blockIdx.x * 4 + os;
  const float* mre = mix_re + (size_t)blk * W * W * M + (size_t)o * M + m;
  const float* mim = mix_im + (size_t)blk * W * W * M + (size_t)o * M + m;
  float gr = 0.f, gi = 0.f;
  for (int i = 0; i < W; ++i){
    float gre = ghat[((size_t)b * W + i) * 128 + 2 * m];
    float gim = ghat[((size_t)b * W + i) * 128 + 2 * m + 1];
    float xr = mre[(size_t)i * W * M];
    float xi = mim[(size_t)i * W * M];
    gr = fmaf(gre, xr, gr); gr = fmaf(-gim, xi, gr);
    gi = fmaf(gre, xi, gi); gi = fmaf( gim, xr, gi);
  }
  int om = blk * W * M + o * M + m;
  float ez = expz[om], ph = phi[om], fl = filt[m];
  size_t vi0 = ((size_t)b * W + o) * 128 + 2 * m;
  float vr = vhat[vi0];
  float vi = vhat[vi0 + 1];
  vhat[vi0] = 0.f;                             // unique reader: zero for next blk
  vhat[vi0 + 1] = 0.f;
  float outr = fmaf(ez, vr, ph * fl * gr);
  float outi = fmaf(ez, vi, ph * fl * gi);
  float sc = ((m == 0) ? 1.0f : 2.0f) / (float)XP;
  outm16[((size_t)b * W + o) * 128 + 2 * m]     = f2bs(outr * sc);
  outm16[((size_t)b * W + o) * 128 + 2 * m + 1] = f2bs(outi * sc);
}

// ---------------- update: h = act(iDFT(out_m) + aw*(W h + b)); split-K ETD ----------------
// LDS 36864 (granule-exact) -> 4 wg/CU. A: hT/basH/xp; B: wwS/omH0; C: omH1.
__global__ __launch_bounds__(256) void k_update(short* __restrict__ h16,
                                                short* __restrict__ hX,
                                                const short* __restrict__ outm16,
                                                const short* __restrict__ basC16,
                                                const short* __restrict__ ww16,
                                                const float* __restrict__ wbg,
                                                const float* __restrict__ awr, int blk){
  __shared__ __align__(16) char smem[36864];
  short (*hT)[72]   = (short(*)[72])smem;              // A: 128x72 = 18432
  short (*basH)[72] = (short(*)[72])smem;              // A reuse
  short (*xp)[72]   = (short(*)[72])smem;              // A reuse (epilogue)
  short (*wwS)[72]  = (short(*)[72])(smem + 18432);    // B: 64x72 = 9216
  short (*omH0)[72] = (short(*)[72])(smem + 18432);    // B reuse
  short (*omH1)[72] = (short(*)[72])(smem + 27648);    // C: 64x72 = 9216
  int b = blockIdx.y, ci = blockIdx.x, x0 = ci * 128, t = threadIdx.x;
  int w = t >> 6, l = t & 63, q = l >> 4, ln = l & 15;
  float aw = softplus_f(awr[0]);
  const short* hXb = hX + (size_t)b * XPAD * 64;
  #pragma unroll
  for (int u = 0; u < 4; ++u){                 // hT from hX rows (vector)
    int idx = u * 256 + t;
    int x = idx >> 3, col = (idx & 7) * 8;
    *(short8*)&hT[x][col] = *(const short8*)&hXb[(size_t)(x0 + x) * 64 + col];
  }
  #pragma unroll
  for (int u = 0; u < 2; ++u){
    int idx = u * 256 + t;
    int o = idx >> 3, col = (idx & 7) * 8;
    *(short8*)&wwS[o][col] = *(const short8*)&ww16[((size_t)blk * W + o) * 64 + col];
  }
  __syncthreads();
  floatx4 acc[2][4];
  #pragma unroll
  for (int mt = 0; mt < 2; ++mt)
    #pragma unroll
    for (int nt = 0; nt < 4; ++nt) acc[mt][nt] = (floatx4){0.f,0.f,0.f,0.f};
  #pragma unroll
  for (int ks = 0; ks < 2; ++ks){              // aw*W@h: K=64
    short8 a0 = *(const short8*)&hT[(w*2+0)*16 + ln][ks*32 + q*8];
    short8 a1 = *(const short8*)&hT[(w*2+1)*16 + ln][ks*32 + q*8];
    #pragma unroll
    for (int nt = 0; nt < 4; ++nt){
      short8 bv = *(const short8*)&wwS[nt*16 + ln][ks*32 + q*8];
      acc[0][nt] = MFMA(a0, bv, acc[0][nt]);
      acc[1][nt] = MFMA(a1, bv, acc[1][nt]);
    }
  }
  __syncthreads();                             // A,B reads done
  #pragma unroll
  for (int u = 0; u < 4; ++u){                 // basC half0 -> A
    int idx = u * 256 + t;
    int x = idx >> 3, col = (idx & 7) * 8;
    *(short8*)&basH[x][col] = *(const short8*)&basC16[(size_t)(x0 + x) * 128 + col];
  }
  #pragma unroll
  for (int u = 0; u < 2; ++u){                 // omS halves -> B, C
    int idx = u * 256 + t;
    int o = idx >> 3, col = (idx & 7) * 8;
    *(short8*)&omH0[o][col] = *(const short8*)&outm16[((size_t)b * W + o) * 128 + col];
    *(short8*)&omH1[o][col] = *(const short8*)&outm16[((size_t)b * W + o) * 128 + 64 + col];
  }
  __syncthreads();
  #pragma unroll
  for (int ks = 0; ks < 2; ++ks){              // etd kp 0..63
    short8 a0 = *(const short8*)&basH[(w*2+0)*16 + ln][ks*32 + q*8];
    short8 a1 = *(const short8*)&basH[(w*2+1)*16 + ln][ks*32 + q*8];
    #pragma unroll
    for (int nt = 0; nt < 4; ++nt){
      short8 bv = *(const short8*)&omH0[nt*16 + ln][ks*32 + q*8];
      acc[0][nt] = MFMA(a0, bv, acc[0][nt]);
      acc[1][nt] = MFMA(a1, bv, acc[1][nt]);
    }
  }
  __syncthreads();                             // A half0 reads done
  #pragma unroll
  for (int u = 0; u < 4; ++u){                 // basC half1 -> A
    int idx = u * 256 + t;
    int x = idx >> 3, col = (idx & 7) * 8;
    *(short8*)&basH[x][col] = *(const short8*)&basC16[(size_t)(x0 + x) * 128 + 64 + col];
  }
  __syncthreads();
  #pragma unroll
  for (int ks = 0; ks < 2; ++ks){              // etd kp 64..127
    short8 a0 = *(const short8*)&basH[(w*2+0)*16 + ln][ks*32 + q*8];
    short8 a1 = *(const short8*)&basH[(w*2+1)*16 + ln][ks*32 + q*8];
    #pragma unroll
    for (int nt = 0; nt < 4; ++nt){
      short8 bv = *(const short8*)&omH1[nt*16 + ln][ks*32 + q*8];
      acc[0][nt] = MFMA(a0, bv, acc[0][nt]);
      acc[1][nt] = MFMA(a1, bv, acc[1][nt]);
    }
  }
  // epilogue: compute bf16 outputs, write h16 directly
  short sreg[2][4][4];
  #pragma unroll
  for (int mt = 0; mt < 2; ++mt)
    #pragma unroll
    for (int nt = 0; nt < 4; ++nt){
      int o = nt*16 + ln;
      int xbase = x0 + (w*2+mt)*16 + q*4;
      float wbv = aw * wbg[blk * W + o];
      short* hp = &h16[((size_t)b * 64 + o) * XPAD + xbase];
      #pragma unroll
      for (int r = 0; r < 4; ++r){
        float u = acc[mt][nt][r] + wbv;
        if (blk != NB - 1) u = gelu_f(u);
        sreg[mt][nt][r] = f2bs(u);
      }
      if (xbase + 3 < XP){
        *(short4*)hp = *(short4*)&sreg[mt][nt][0];
      } else {
        #pragma unroll
        for (int r = 0; r < 4; ++r)
          if (xbase + r < XP) hp[r] = sreg[mt][nt][r];
      }
    }
  __syncthreads();                             // A/C reads done
  #pragma unroll
  for (int mt = 0; mt < 2; ++mt)
    #pragma unroll
    for (int nt = 0; nt < 4; ++nt){
      int o = nt*16 + ln;
      int xl = (w*2+mt)*16 + q*4;
      #pragma unroll
      for (int r = 0; r < 4; ++r) xp[xl + r][o] = sreg[mt][nt][r];
    }
  __syncthreads();
  #pragma unroll
  for (int u = 0; u < 4; ++u){
    int idx = u * 256 + t;
    int x = idx >> 3, col = (idx & 7) * 8;
    if (x0 + x < XP)
      *(short8*)&hX[((size_t)b * XPAD + x0 + x) * 64 + col] = *(const short8*)&xp[x][col];
  }
}

// ---------------- fc12: MFMA fc1 + VALU fc2 -> out (fp32) ----------------
__global__ __launch_bounds__(256) void k_fc12(const short* __restrict__ hX,
                                              const short* __restrict__ w1fc16,
                                              const float* __restrict__ b1,
                                              const float* __restrict__ w2,
                                              const float* __restrict__ b2,
                                              float* __restrict__ out){
  __shared__ short hT[128][72];
  __shared__ short gT[128][136];
  __shared__ float w2s[NC][132];
  __shared__ float red[2][128][NC];
  int b = blockIdx.y, x0 = blockIdx.x * 128, t = threadIdx.x;
  int w = t >> 6, l = t & 63, q = l >> 4, ln = l & 15;
  const short* hXb = hX + (size_t)b * XPAD * 64;
  #pragma unroll
  for (int u = 0; u < 4; ++u){
    int idx = u * 256 + t;
    int x = idx >> 3, col = (idx & 7) * 8;
    *(short8*)&hT[x][col] = *(const short8*)&hXb[(size_t)(x0 + x) * 64 + col];
  }
  for (int i = t; i < NC * H; i += 256) w2s[i / H][i % H] = w2[i];
  __syncthreads();
  floatx4 acc[2][8];
  #pragma unroll
  for (int mt = 0; mt < 2; ++mt)
    #pragma unroll
    for (int nt = 0; nt < 8; ++nt) acc[mt][nt] = (floatx4){0.f,0.f,0.f,0.f};
  #pragma unroll
  for (int ks = 0; ks < 2; ++ks){
    short8 a0 = *(const short8*)&w1fc16[(size_t)((w*2+0)*16 + ln) * 64 + ks*32 + q*8];
    short8 a1 = *(const short8*)&w1fc16[(size_t)((w*2+1)*16 + ln) * 64 + ks*32 + q*8];
    #pragma unroll
    for (int nt = 0; nt < 8; ++nt){
      short8 bv = *(const short8*)&hT[nt*16 + ln][ks*32 + q*8];
      acc[0][nt] = MFMA(a0, bv, acc[0][nt]);
      acc[1][nt] = MFMA(a1, bv, acc[1][nt]);
    }
  }
  #pragma unroll
  for (int mt = 0; mt < 2; ++mt){
    float bvv[4];
    #pragma unroll
    for (int r = 0; r < 4; ++r) bvv[r] = b1[(w*2+mt)*16 + q*4 + r];
    #pragma unroll
    for (int nt = 0; nt < 8; ++nt){
      int x = nt*16 + ln;
      #pragma unroll
      for (int r = 0; r < 4; ++r)
        gT[x][(w*2+mt)*16 + q*4 + r] = f2bs(gelu_f(acc[mt][nt][r] + bvv[r]));
    }
  }
  __syncthreads();
  int x = t & 127, half = t >> 7;
  float a3[NC] = {0.f, 0.f, 0.f};
  for (int og = 0; og < 8; ++og){
    int o0 = half * 64 + og * 8;
    short8 gv = *(const short8*)&gT[x][o0];
    #pragma unroll
    for (int j = 0; j < 8; ++j){
      float gf = bs2f(gv[j]);
      #pragma unroll
      for (int n = 0; n < NC; ++n) a3[n] = fmaf(gf, w2s[n][o0 + j], a3[n]);
    }
  }
  #pragma unroll
  for (int n = 0; n < NC; ++n) red[half][x][n] = a3[n];
  __syncthreads();
  if (half == 0){
    #pragma unroll
    for (int n = 0; n < NC; ++n)
      out[((size_t)b * X + x0 + x) * NC + n] = red[0][x][n] + red[1][x][n] + b2[n];
  }
}

extern "C" void kernel_launch(void* const* d_in, const int* in_sizes, int n_in,
                              void* d_out, int out_size, void* d_ws, size_t ws_size,
                              hipStream_t stream){
  (void)in_sizes; (void)n_in; (void)out_size; (void)ws_size;
  const float* x        = (const float*)d_in[0];
  const float* grid     = (const float*)d_in[1];
  const float* fc0_w    = (const float*)d_in[2];
  const float* fc0_b    = (const float*)d_in[3];
  const float* fc1_w    = (const float*)d_in[4];
  const float* fc1_b    = (const float*)d_in[5];
  const float* fc2_w    = (const float*)d_in[6];
  const float* fc2_b    = (const float*)d_in[7];
  const float* g_w1     = (const float*)d_in[8];
  const float* g_b1     = (const float*)d_in[9];
  const float* g_w2     = (const float*)d_in[10];
  const float* g_b2     = (const float*)d_in[11];
  const float* w_w      = (const float*)d_in[12];
  const float* w_b      = (const float*)d_in[13];
  const float* log_dec  = (const float*)d_in[14];
  const float* mix_re   = (const float*)d_in[15];
  const float* mix_im   = (const float*)d_in[16];
  const float* a_w      = (const float*)d_in[17];
  const float* a_g      = (const float*)d_in[18];
  float* out = (float*)d_out;

  // workspace carve (~78 MB, 16B aligned)
  short* basC16 = (short*)d_ws;                         // XPAD*128
  short* basT16 = basC16 + (size_t)XPAD * 128;          // 128*XPAD
  short* h16    = basT16 + (size_t)128 * XPAD;          // BB*64*XPAD
  short* hX     = h16 + (size_t)BB * 64 * XPAD;         // BB*XPAD*64
  float* vhat   = (float*)(hX + (size_t)BB * XPAD * 64);
  float* gmidhat= vhat + (size_t)BB * W * 128;
  float* ghat   = gmidhat + (size_t)BB * H * 128;
  float* expz   = ghat + (size_t)BB * W * 128;
  float* phi    = expz + NB * W * M;
  float* filt   = phi + NB * W * M;
  short* outm16 = (short*)(filt + 64);
  short* ww16   = outm16 + (size_t)BB * W * 128;
  short* w116   = ww16 + NB * W * W;
  short* w1fc16 = w116 + NB * H * W;
  short* w0fc16 = w1fc16 + H * W;

  k_basis2<<<dim3((2 * 128 * XPAD + 255) / 256), 256, 0, stream>>>(basT16, basC16);
  k_prep2<<<dim3((16384 + 64 + 59392 + 255) / 256), 256, 0, stream>>>(
      log_dec, w_w, g_w1, fc1_w, fc0_w, a_w, expz, phi, filt, ww16, w116, w1fc16, w0fc16);
  k_fc0m<<<dim3(129, BB), 256, 0, stream>>>(x, grid, w0fc16, fc0_b, h16, hX);
  hipMemsetAsync(vhat, 0, (size_t)(BB * W * 128 + BB * H * 128) * sizeof(float), stream);

  for (int blk = 0; blk < NB; ++blk){
    k_dft<<<dim3(16, BB, 3), 256, 0, stream>>>(h16, hX, w116, g_b1, basT16, vhat, gmidhat, blk);
    k_ghat<<<dim3(BB, 32), 256, 0, stream>>>(gmidhat, g_w2, g_b2, a_g, ghat, blk);
    k_outm<<<dim3(16, BB), 256, 0, stream>>>(vhat, ghat, mix_re, mix_im, expz, phi, filt, outm16, blk);
    k_update<<<dim3(XPAD / 128, BB), 256, 0, stream>>>(h16, hX, outm16, basC16, ww16, w_b, a_w, blk);
  }
  k_fc12<<<dim3(X / 128, BB), 256, 0, stream>>>(hX, w1fc16, fc1_b, fc2_w, fc2_b, out);
}

// Round 19
// 571.274 us; speedup vs baseline: 1.1508x; 1.0604x over previous
//
#include <hip/hip_runtime.h>
#include <hip/hip_bf16.h>

// SGNO1d: B=16, X=16384, Xp=16386, W=64, H=128, M=64, NB=4.
// MFMA bf16 pipeline. h in two layouts: h16[b][c][XPAD] + hX[b][x][64].
// R19 = R18 (best, 606us) with ONE change: k_outm i-loop split 4-way
// (grid (64,BB) -> 4 wg/CU vs 1; R18's k_outm ran 256 wgs on 256 CUs with a
// 64-deep serial load chain -- zero latency hiding).

#define BB 16
#define X 16384
#define XP 16386
#define XPAD 16512   // 129*128; rows 16B-aligned, pad zeros
#define W 64
#define H 128
#define M 64
#define NB 4
#define NC 3

typedef __hip_bfloat16 bf16;
typedef __attribute__((ext_vector_type(8))) short short8;
typedef __attribute__((ext_vector_type(4))) float floatx4;

__device__ __forceinline__ float gelu_f(float x){
  // gelu(x) = x * sigmoid(1.5957691216 x + 0.0713548162 x^3)  (== tanh form)
  float x2 = x * x;
  float inner = fmaf(0.0713548162f, x2, 1.5957691216f);
  float e = __expf(-x * inner);
  return x / (1.f + e);
}
__device__ __forceinline__ float softplus_f(float v){
  return (v > 20.f) ? v : log1pf(expf(v));
}
__device__ __forceinline__ short f2bs(float f){   // fp32 -> bf16 bits (RNE)
  union { float f; unsigned u; } v; v.f = f;
  unsigned r = (v.u + 0x7FFFu + ((v.u >> 16) & 1u)) >> 16;
  return (short)r;
}
__device__ __forceinline__ float bs2f(short s){
  union { unsigned u; float f; } v; v.u = ((unsigned)(unsigned short)s) << 16;
  return v.f;
}
#define MFMA(a,b,c) __builtin_amdgcn_mfma_f32_16x16x32_bf16((a),(b),(c),0,0,0)

// ---------------- bases (fused, coalesced writes) ----------------
__global__ __launch_bounds__(256) void k_basis2(short* __restrict__ basT16,
                                                short* __restrict__ basC16){
  int idx = blockIdx.x * 256 + threadIdx.x;
  const int N1 = 128 * XPAD;
  if (idx < N1){
    int mp = idx / XPAD, x = idx - mp * XPAD;
    float v = 0.f;
    if (x < XP){
      int m = mp >> 1;
      int tt = (int)(((long long)x * (long long)m) % XP);
      float ang = 6.283185307179586477f * (float)tt / (float)XP;
      float s, c; sincosf(ang, &s, &c);
      v = (mp & 1) ? s : c;
    }
    basT16[idx] = f2bs(v);
  } else if (idx < 2 * N1){
    int i = idx - N1;
    int x = i >> 7, kp = i & 127;
    float v = 0.f;
    if (x < XP){
      int m = kp >> 1;
      int tt = (int)(((long long)x * (long long)m) % XP);
      float ang = 6.283185307179586477f * (float)tt / (float)XP;
      float s, c; sincosf(ang, &s, &c);
      v = (kp & 1) ? -s : c;
    }
    basC16[i] = f2bs(v);
  }
}

// ---------------- fused prep: decay + filt + bf16 weight copies ----------------
__global__ __launch_bounds__(256) void k_prep2(const float* __restrict__ log_decay,
                                               const float* __restrict__ w_w,
                                               const float* __restrict__ g_w1,
                                               const float* __restrict__ fc1_w,
                                               const float* __restrict__ fc0_w,
                                               const float* __restrict__ awr,
                                               float* __restrict__ expz,
                                               float* __restrict__ phi,
                                               float* __restrict__ filt,
                                               short* __restrict__ ww16,
                                               short* __restrict__ w116,
                                               short* __restrict__ w1fc16,
                                               short* __restrict__ w0fc16){
  int idx = blockIdx.x * 256 + threadIdx.x;
  if (idx < 16384){                       // decay (NB*W*M)
    float z = -softplus_f(log_decay[idx]);
    expz[idx] = expf(z);
    float p;
    if (fabsf(z) < 1e-6f) p = 1.0f + 0.5f * z + z * z * (1.0f / 6.0f);
    else                  p = expm1f(z) / z;
    phi[idx] = p;
    return;
  }
  int j = idx - 16384;
  if (j < 64){                            // filt
    float g = (float)j / 63.0f;
    float r2 = g * g + 1e-12f;
    float r4 = r2 * r2;
    float r8 = r4 * r4;
    filt[j] = expf(-2.0f * r8);
    return;
  }
  j -= 64;
  float aw = softplus_f(awr[0]);
  if (j < 16384){ ww16[j] = f2bs(aw * w_w[j]); }
  else if (j < 49152){ int i = j - 16384; w116[i] = f2bs(g_w1[i]); }
  else if (j < 57344){ int i = j - 49152; w1fc16[i] = f2bs(fc1_w[i]); }
  else if (j < 59392){
    int i = j - 57344;
    int o = i >> 5, f = i & 31;
    w0fc16[i] = (f < 31) ? f2bs(fc0_w[o * 31 + f]) : (short)0;
  }
}

// ---------------- fc0 (MFMA): h16 + hX, pad zeros ----------------
__global__ __launch_bounds__(256) void k_fc0m(const float* __restrict__ xg,
                                              const float* __restrict__ gg,
                                              const short* __restrict__ w0fc16,
                                              const float* __restrict__ bg,
                                              short* __restrict__ h16,
                                              short* __restrict__ hX){
  __shared__ short xs16[128][40];
  __shared__ short xp[128][72];
  int b = blockIdx.y, bx = blockIdx.x, x0 = bx * 128, t = threadIdx.x;
  if (bx == 128){                       // pad rows: zero h16 & hX
    for (int i = t; i < 64 * 128; i += 256){
      int c = i >> 7, x = i & 127;
      h16[((size_t)b * 64 + c) * XPAD + x0 + x] = 0;
    }
    short8 z8 = (short8){0,0,0,0,0,0,0,0};
    for (int u = 0; u < 4; ++u){
      int idx = u * 256 + t;
      int x = idx >> 3, col = (idx & 7) * 8;
      *(short8*)&hX[((size_t)b * XPAD + x0 + x) * 64 + col] = z8;
    }
    return;
  }
  for (int i = t; i < 3840; i += 256){
    int x = i / 30, f = i - x * 30;
    xs16[x][f] = f2bs(xg[((size_t)b * X + x0 + x) * 30 + f]);
  }
  if (t < 128){ xs16[t][30] = f2bs(gg[(size_t)b * X + x0 + t]); xs16[t][31] = 0; }
  __syncthreads();
  int w = t >> 6, l = t & 63, q = l >> 4, ln = l & 15;
  floatx4 acc[4][2];
  #pragma unroll
  for (int mt = 0; mt < 4; ++mt)
    #pragma unroll
    for (int nt = 0; nt < 2; ++nt) acc[mt][nt] = (floatx4){0.f,0.f,0.f,0.f};
  #pragma unroll
  for (int mt = 0; mt < 4; ++mt){
    short8 av = *(const short8*)&w0fc16[(mt * 16 + ln) * 32 + q * 8];
    #pragma unroll
    for (int nt = 0; nt < 2; ++nt){
      short8 bv = *(const short8*)&xs16[w * 32 + nt * 16 + ln][q * 8];
      acc[mt][nt] = MFMA(av, bv, acc[mt][nt]);
    }
  }
  #pragma unroll
  for (int mt = 0; mt < 4; ++mt)
    #pragma unroll
    for (int r = 0; r < 4; ++r){
      int o = mt * 16 + q * 4 + r;
      float bias = bg[o];
      #pragma unroll
      for (int nt = 0; nt < 2; ++nt){
        int xl = w * 32 + nt * 16 + ln;
        short s = f2bs(acc[mt][nt][r] + bias);
        h16[((size_t)b * 64 + o) * XPAD + x0 + xl] = s;
        xp[xl][o] = s;
      }
    }
  __syncthreads();
  #pragma unroll
  for (int u = 0; u < 4; ++u){
    int idx = u * 256 + t;
    int x = idx >> 3, col = (idx & 7) * 8;
    *(short8*)&hX[((size_t)b * XPAD + x0 + x) * 64 + col] = *(const short8*)&xp[x][col];
  }
}

// ---------------- DFT (64 modes) with fused gmid, MFMA split-K, fp32 atomics ----------------
// R14-exact: stride 136, LDS 52224 (3 wg/CU), grid (16, BB, 3), ci < 129.
__global__ __launch_bounds__(256) void k_dft(const short* __restrict__ h16,
                                             const short* __restrict__ hX,
                                             const short* __restrict__ w116,
                                             const float* __restrict__ b1g,
                                             const short* __restrict__ basT16,
                                             float* __restrict__ vhat,
                                             float* __restrict__ gmidhat, int blk){
  __shared__ __align__(16) char smem[52224];
  short (*srcT)[136] = (short(*)[136])smem;            // 64x136, persistent
  short (*hT)[72]    = (short(*)[72])(smem + 17408);   // 128x72, W1 phase
  short (*basS)[136] = (short(*)[136])(smem + 17408);  // 128x136, DFT phase
  int b = blockIdx.y, z = blockIdx.z, bx = blockIdx.x, t = threadIdx.x;
  int w = t >> 6, l = t & 63, q = l >> 4, ln = l & 15;
  const short* hbase = h16 + (size_t)b * 64 * XPAD;
  const short* hXb   = hX + (size_t)b * XPAD * 64;
  floatx4 acc[8];
  #pragma unroll
  for (int i = 0; i < 8; ++i) acc[i] = (floatx4){0.f,0.f,0.f,0.f};
  short8 aw1[2];
  float bias[4];
  if (z){
    #pragma unroll
    for (int ks = 0; ks < 2; ++ks)
      aw1[ks] = *(const short8*)&w116[((size_t)blk * H + (z-1)*64 + w*16 + ln) * 64 + ks*32 + q*8];
    #pragma unroll
    for (int r = 0; r < 4; ++r)
      bias[r] = b1g[blk * H + (z-1)*64 + w*16 + q*4 + r];
  }
  for (int ci = bx; ci < 129; ci += 16){
    int xc = ci * 128;
    __syncthreads();                           // prior-iter LDS reads done
    if (z == 0){
      #pragma unroll
      for (int u = 0; u < 4; ++u){
        int idx = u * 256 + t;
        int c = idx >> 4, col = (idx & 15) * 8;
        *(short8*)&srcT[c][col] = *(const short8*)&hbase[(size_t)c * XPAD + xc + col];
      }
    } else {
      #pragma unroll
      for (int u = 0; u < 4; ++u){             // hT[x][c] from hX rows (vector)
        int idx = u * 256 + t;
        int x = idx >> 3, col = (idx & 7) * 8;
        *(short8*)&hT[x][col] = *(const short8*)&hXb[(size_t)(xc + x) * 64 + col];
      }
    }
    __syncthreads();
    if (z){
      floatx4 a2[8];
      #pragma unroll
      for (int i = 0; i < 8; ++i) a2[i] = (floatx4){0.f,0.f,0.f,0.f};
      #pragma unroll
      for (int ks = 0; ks < 2; ++ks){
        #pragma unroll
        for (int nt = 0; nt < 8; ++nt){
          short8 bv = *(const short8*)&hT[nt*16 + ln][ks*32 + q*8];
          a2[nt] = MFMA(aw1[ks], bv, a2[nt]);
        }
      }
      #pragma unroll
      for (int nt = 0; nt < 8; ++nt){
        int gx = xc + nt*16 + ln;
        #pragma unroll
        for (int r = 0; r < 4; ++r){
          int o = w*16 + q*4 + r;
          float vv = gelu_f(a2[nt][r] + bias[r]);
          srcT[o][nt*16 + ln] = (gx < XP) ? f2bs(vv) : (short)0;
        }
      }
    }
    __syncthreads();                           // hT reads done; srcT visible
    #pragma unroll
    for (int u = 0; u < 8; ++u){
      int idx = u * 256 + t;
      int mp = idx >> 4, col = (idx & 15) * 8;
      *(short8*)&basS[mp][col] = *(const short8*)&basT16[(size_t)mp * XPAD + xc + col];
    }
    __syncthreads();
    #pragma unroll
    for (int ks = 0; ks < 4; ++ks){
      short8 av = *(const short8*)&srcT[w*16 + ln][ks*32 + q*8];
      #pragma unroll
      for (int nt = 0; nt < 8; ++nt){
        short8 bv = *(const short8*)&basS[nt*16 + ln][ks*32 + q*8];
        acc[nt] = MFMA(av, bv, acc[nt]);
      }
    }
  }
  #pragma unroll
  for (int nt = 0; nt < 8; ++nt)
    #pragma unroll
    for (int r = 0; r < 4; ++r){
      int mp = nt*16 + ln;
      int c  = w*16 + q*4 + r;
      float v = acc[nt][r];
      if (mp & 1) v = -v;                      // im = -sum(src*sin)
      if (z == 0) atomicAdd(&vhat[((size_t)b * W + c) * 128 + mp], v);
      else atomicAdd(&gmidhat[((size_t)b * H + (z-1)*64 + c) * 128 + mp], v);
    }
}

// ---------------- ghat = ag*(W2 @ gmidhat) + ag*b2*XP at m=0 ----------------
// grid (BB, 32): 1 mp per thread; zeroes gmidhat slice after reads.
__global__ __launch_bounds__(256) void k_ghat(float* __restrict__ gmidhat,
                                              const float* __restrict__ w2g,
                                              const float* __restrict__ b2g,
                                              const float* __restrict__ agr,
                                              float* __restrict__ ghat, int blk){
  __shared__ float w2s[64][133];
  int b = blockIdx.x, zg = blockIdx.y, t = threadIdx.x;
  float ag = softplus_f(agr[0]);
  for (int i = t; i < 8192; i += 256) w2s[i >> 7][i & 127] = w2g[(size_t)blk * 8192 + i];
  __syncthreads();
  int i = t & 63, ms = t >> 6;
  int mp = zg * 4 + ms;
  float acc = 0.f;
  for (int c2 = 0; c2 < H; ++c2)
    acc = fmaf(w2s[i][c2], gmidhat[((size_t)b * H + c2) * 128 + mp], acc);
  if (mp == 0) acc += (float)XP * b2g[blk * W + i];
  ghat[((size_t)b * W + i) * 128 + mp] = ag * acc;
  __syncthreads();                             // all reads of gmidhat done
  for (int u = t; u < 512; u += 256){          // zero slice for next blk
    int c2 = u >> 2, j = u & 3;
    gmidhat[((size_t)b * H + c2) * 128 + zg * 4 + j] = 0.f;
  }
}

// ---------------- out_m: 4-way i-split (grid (64,BB), 4 wg/CU); zeroes vhat ----------------
__global__ __launch_bounds__(256) void k_outm(float* __restrict__ vhat,
                       const float* __restrict__ ghat,
                       const float* __restrict__ mix_re, const float* __restrict__ mix_im,
                       const float* __restrict__ expz, const float* __restrict__ phi,
                       const float* __restrict__ filt, short* __restrict__ outm16, int blk){
  __shared__ float red[4][64][2];
  int b = blockIdx.y, o = blockIdx.x, t = threadIdx.x;
  int m = t & 63, os = t >> 6;                 // os = i-quarter
  const float* mre = mix_re + (size_t)blk * W * W * M + (size_t)o * M + m;
  const float* mim = mix_im + (size_t)blk * W * W * M + (size_t)o * M + m;
  float gr = 0.f, gi = 0.f;
  int i0 = os * 16;
  for (int i = i0; i < i0 + 16; ++i){
    float gre = ghat[((size_t)b * W + i) * 128 + 2 * m];
    float gim = ghat[((size_t)b * W + i) * 128 + 2 * m + 1];
    float xr = mre[(size_t)i * W * M];
    float xi = mim[(size_t)i * W * M];
    gr = fmaf(gre, xr, gr); gr = fmaf(-gim, xi, gr);
    gi = fmaf(gre, xi, gi); gi = fmaf( gim, xr, gi);
  }
  red[os][m][0] = gr;
  red[os][m][1] = gi;
  __syncthreads();
  if (os == 0){
    gr = red[0][m][0] + red[1][m][0] + red[2][m][0] + red[3][m][0];
    gi = red[0][m][1] + red[1][m][1] + red[2][m][1] + red[3][m][1];
    int om = blk * W * M + o * M + m;
    float ez = expz[om], ph = phi[om], fl = filt[m];
    size_t vi0 = ((size_t)b * W + o) * 128 + 2 * m;
    float vr = vhat[vi0];
    float vi = vhat[vi0 + 1];
    vhat[vi0] = 0.f;                           // unique reader: zero for next blk
    vhat[vi0 + 1] = 0.f;
    float outr = fmaf(ez, vr, ph * fl * gr);
    float outi = fmaf(ez, vi, ph * fl * gi);
    float sc = ((m == 0) ? 1.0f : 2.0f) / (float)XP;
    outm16[((size_t)b * W + o) * 128 + 2 * m]     = f2bs(outr * sc);
    outm16[((size_t)b * W + o) * 128 + 2 * m + 1] = f2bs(outi * sc);
  }
}

// ---------------- update: h = act(iDFT(out_m) + aw*(W h + b)); split-K ETD ----------------
// LDS 36864 (granule-exact) -> 4 wg/CU. A: hT/basH/xp; B: wwS/omH0; C: omH1.
__global__ __launch_bounds__(256) void k_update(short* __restrict__ h16,
                                                short* __restrict__ hX,
                                                const short* __restrict__ outm16,
                                                const short* __restrict__ basC16,
                                                const short* __restrict__ ww16,
                                                const float* __restrict__ wbg,
                                                const float* __restrict__ awr, int blk){
  __shared__ __align__(16) char smem[36864];
  short (*hT)[72]   = (short(*)[72])smem;              // A: 128x72 = 18432
  short (*basH)[72] = (short(*)[72])smem;              // A reuse
  short (*xp)[72]   = (short(*)[72])smem;              // A reuse (epilogue)
  short (*wwS)[72]  = (short(*)[72])(smem + 18432);    // B: 64x72 = 9216
  short (*omH0)[72] = (short(*)[72])(smem + 18432);    // B reuse
  short (*omH1)[72] = (short(*)[72])(smem + 27648);    // C: 64x72 = 9216
  int b = blockIdx.y, ci = blockIdx.x, x0 = ci * 128, t = threadIdx.x;
  int w = t >> 6, l = t & 63, q = l >> 4, ln = l & 15;
  float aw = softplus_f(awr[0]);
  const short* hXb = hX + (size_t)b * XPAD * 64;
  #pragma unroll
  for (int u = 0; u < 4; ++u){                 // hT from hX rows (vector)
    int idx = u * 256 + t;
    int x = idx >> 3, col = (idx & 7) * 8;
    *(short8*)&hT[x][col] = *(const short8*)&hXb[(size_t)(x0 + x) * 64 + col];
  }
  #pragma unroll
  for (int u = 0; u < 2; ++u){
    int idx = u * 256 + t;
    int o = idx >> 3, col = (idx & 7) * 8;
    *(short8*)&wwS[o][col] = *(const short8*)&ww16[((size_t)blk * W + o) * 64 + col];
  }
  __syncthreads();
  floatx4 acc[2][4];
  #pragma unroll
  for (int mt = 0; mt < 2; ++mt)
    #pragma unroll
    for (int nt = 0; nt < 4; ++nt) acc[mt][nt] = (floatx4){0.f,0.f,0.f,0.f};
  #pragma unroll
  for (int ks = 0; ks < 2; ++ks){              // aw*W@h: K=64
    short8 a0 = *(const short8*)&hT[(w*2+0)*16 + ln][ks*32 + q*8];
    short8 a1 = *(const short8*)&hT[(w*2+1)*16 + ln][ks*32 + q*8];
    #pragma unroll
    for (int nt = 0; nt < 4; ++nt){
      short8 bv = *(const short8*)&wwS[nt*16 + ln][ks*32 + q*8];
      acc[0][nt] = MFMA(a0, bv, acc[0][nt]);
      acc[1][nt] = MFMA(a1, bv, acc[1][nt]);
    }
  }
  __syncthreads();                             // A,B reads done
  #pragma unroll
  for (int u = 0; u < 4; ++u){                 // basC half0 -> A
    int idx = u * 256 + t;
    int x = idx >> 3, col = (idx & 7) * 8;
    *(short8*)&basH[x][col] = *(const short8*)&basC16[(size_t)(x0 + x) * 128 + col];
  }
  #pragma unroll
  for (int u = 0; u < 2; ++u){                 // omS halves -> B, C
    int idx = u * 256 + t;
    int o = idx >> 3, col = (idx & 7) * 8;
    *(short8*)&omH0[o][col] = *(const short8*)&outm16[((size_t)b * W + o) * 128 + col];
    *(short8*)&omH1[o][col] = *(const short8*)&outm16[((size_t)b * W + o) * 128 + 64 + col];
  }
  __syncthreads();
  #pragma unroll
  for (int ks = 0; ks < 2; ++ks){              // etd kp 0..63
    short8 a0 = *(const short8*)&basH[(w*2+0)*16 + ln][ks*32 + q*8];
    short8 a1 = *(const short8*)&basH[(w*2+1)*16 + ln][ks*32 + q*8];
    #pragma unroll
    for (int nt = 0; nt < 4; ++nt){
      short8 bv = *(const short8*)&omH0[nt*16 + ln][ks*32 + q*8];
      acc[0][nt] = MFMA(a0, bv, acc[0][nt]);
      acc[1][nt] = MFMA(a1, bv, acc[1][nt]);
    }
  }
  __syncthreads();                             // A half0 reads done
  #pragma unroll
  for (int u = 0; u < 4; ++u){                 // basC half1 -> A
    int idx = u * 256 + t;
    int x = idx >> 3, col = (idx & 7) * 8;
    *(short8*)&basH[x][col] = *(const short8*)&basC16[(size_t)(x0 + x) * 128 + 64 + col];
  }
  __syncthreads();
  #pragma unroll
  for (int ks = 0; ks < 2; ++ks){              // etd kp 64..127
    short8 a0 = *(const short8*)&basH[(w*2+0)*16 + ln][ks*32 + q*8];
    short8 a1 = *(const short8*)&basH[(w*2+1)*16 + ln][ks*32 + q*8];
    #pragma unroll
    for (int nt = 0; nt < 4; ++nt){
      short8 bv = *(const short8*)&omH1[nt*16 + ln][ks*32 + q*8];
      acc[0][nt] = MFMA(a0, bv, acc[0][nt]);
      acc[1][nt] = MFMA(a1, bv, acc[1][nt]);
    }
  }
  // epilogue: compute bf16 outputs, write h16 directly
  short sreg[2][4][4];
  #pragma unroll
  for (int mt = 0; mt < 2; ++mt)
    #pragma unroll
    for (int nt = 0; nt < 4; ++nt){
      int o = nt*16 + ln;
      int xbase = x0 + (w*2+mt)*16 + q*4;
      float wbv = aw * wbg[blk * W + o];
      short* hp = &h16[((size_t)b * 64 + o) * XPAD + xbase];
      #pragma unroll
      for (int r = 0; r < 4; ++r){
        float u = acc[mt][nt][r] + wbv;
        if (blk != NB - 1) u = gelu_f(u);
        sreg[mt][nt][r] = f2bs(u);
      }
      if (xbase + 3 < XP){
        *(short4*)hp = *(short4*)&sreg[mt][nt][0];
      } else {
        #pragma unroll
        for (int r = 0; r < 4; ++r)
          if (xbase + r < XP) hp[r] = sreg[mt][nt][r];
      }
    }
  __syncthreads();                             // A/C reads done
  #pragma unroll
  for (int mt = 0; mt < 2; ++mt)
    #pragma unroll
    for (int nt = 0; nt < 4; ++nt){
      int o = nt*16 + ln;
      int xl = (w*2+mt)*16 + q*4;
      #pragma unroll
      for (int r = 0; r < 4; ++r) xp[xl + r][o] = sreg[mt][nt][r];
    }
  __syncthreads();
  #pragma unroll
  for (int u = 0; u < 4; ++u){
    int idx = u * 256 + t;
    int x = idx >> 3, col = (idx & 7) * 8;
    if (x0 + x < XP)
      *(short8*)&hX[((size_t)b * XPAD + x0 + x) * 64 + col] = *(const short8*)&xp[x][col];
  }
}

// ---------------- fc12: MFMA fc1 + VALU fc2 -> out (fp32) ----------------
__global__ __launch_bounds__(256) void k_fc12(const short* __restrict__ hX,
                                              const short* __restrict__ w1fc16,
                                              const float* __restrict__ b1,
                                              const float* __restrict__ w2,
                                              const float* __restrict__ b2,
                                              float* __restrict__ out){
  __shared__ short hT[128][72];
  __shared__ short gT[128][136];
  __shared__ float w2s[NC][132];
  __shared__ float red[2][128][NC];
  int b = blockIdx.y, x0 = blockIdx.x * 128, t = threadIdx.x;
  int w = t >> 6, l = t & 63, q = l >> 4, ln = l & 15;
  const short* hXb = hX + (size_t)b * XPAD * 64;
  #pragma unroll
  for (int u = 0; u < 4; ++u){
    int idx = u * 256 + t;
    int x = idx >> 3, col = (idx & 7) * 8;
    *(short8*)&hT[x][col] = *(const short8*)&hXb[(size_t)(x0 + x) * 64 + col];
  }
  for (int i = t; i < NC * H; i += 256) w2s[i / H][i % H] = w2[i];
  __syncthreads();
  floatx4 acc[2][8];
  #pragma unroll
  for (int mt = 0; mt < 2; ++mt)
    #pragma unroll
    for (int nt = 0; nt < 8; ++nt) acc[mt][nt] = (floatx4){0.f,0.f,0.f,0.f};
  #pragma unroll
  for (int ks = 0; ks < 2; ++ks){
    short8 a0 = *(const short8*)&w1fc16[(size_t)((w*2+0)*16 + ln) * 64 + ks*32 + q*8];
    short8 a1 = *(const short8*)&w1fc16[(size_t)((w*2+1)*16 + ln) * 64 + ks*32 + q*8];
    #pragma unroll
    for (int nt = 0; nt < 8; ++nt){
      short8 bv = *(const short8*)&hT[nt*16 + ln][ks*32 + q*8];
      acc[0][nt] = MFMA(a0, bv, acc[0][nt]);
      acc[1][nt] = MFMA(a1, bv, acc[1][nt]);
    }
  }
  #pragma unroll
  for (int mt = 0; mt < 2; ++mt){
    float bvv[4];
    #pragma unroll
    for (int r = 0; r < 4; ++r) bvv[r] = b1[(w*2+mt)*16 + q*4 + r];
    #pragma unroll
    for (int nt = 0; nt < 8; ++nt){
      int x = nt*16 + ln;
      #pragma unroll
      for (int r = 0; r < 4; ++r)
        gT[x][(w*2+mt)*16 + q*4 + r] = f2bs(gelu_f(acc[mt][nt][r] + bvv[r]));
    }
  }
  __syncthreads();
  int x = t & 127, half = t >> 7;
  float a3[NC] = {0.f, 0.f, 0.f};
  for (int og = 0; og < 8; ++og){
    int o0 = half * 64 + og * 8;
    short8 gv = *(const short8*)&gT[x][o0];
    #pragma unroll
    for (int j = 0; j < 8; ++j){
      float gf = bs2f(gv[j]);
      #pragma unroll
      for (int n = 0; n < NC; ++n) a3[n] = fmaf(gf, w2s[n][o0 + j], a3[n]);
    }
  }
  #pragma unroll
  for (int n = 0; n < NC; ++n) red[half][x][n] = a3[n];
  __syncthreads();
  if (half == 0){
    #pragma unroll
    for (int n = 0; n < NC; ++n)
      out[((size_t)b * X + x0 + x) * NC + n] = red[0][x][n] + red[1][x][n] + b2[n];
  }
}

extern "C" void kernel_launch(void* const* d_in, const int* in_sizes, int n_in,
                              void* d_out, int out_size, void* d_ws, size_t ws_size,
                              hipStream_t stream){
  (void)in_sizes; (void)n_in; (void)out_size; (void)ws_size;
  const float* x        = (const float*)d_in[0];
  const float* grid     = (const float*)d_in[1];
  const float* fc0_w    = (const float*)d_in[2];
  const float* fc0_b    = (const float*)d_in[3];
  const float* fc1_w    = (const float*)d_in[4];
  const float* fc1_b    = (const float*)d_in[5];
  const float* fc2_w    = (const float*)d_in[6];
  const float* fc2_b    = (const float*)d_in[7];
  const float* g_w1     = (const float*)d_in[8];
  const float* g_b1     = (const float*)d_in[9];
  const float* g_w2     = (const float*)d_in[10];
  const float* g_b2     = (const float*)d_in[11];
  const float* w_w      = (const float*)d_in[12];
  const float* w_b      = (const float*)d_in[13];
  const float* log_dec  = (const float*)d_in[14];
  const float* mix_re   = (const float*)d_in[15];
  const float* mix_im   = (const float*)d_in[16];
  const float* a_w      = (const float*)d_in[17];
  const float* a_g      = (const float*)d_in[18];
  float* out = (float*)d_out;

  // workspace carve (~78 MB, 16B aligned)
  short* basC16 = (short*)d_ws;                         // XPAD*128
  short* basT16 = basC16 + (size_t)XPAD * 128;          // 128*XPAD
  short* h16    = basT16 + (size_t)128 * XPAD;          // BB*64*XPAD
  short* hX     = h16 + (size_t)BB * 64 * XPAD;         // BB*XPAD*64
  float* vhat   = (float*)(hX + (size_t)BB * XPAD * 64);
  float* gmidhat= vhat + (size_t)BB * W * 128;
  float* ghat   = gmidhat + (size_t)BB * H * 128;
  float* expz   = ghat + (size_t)BB * W * 128;
  float* phi    = expz + NB * W * M;
  float* filt   = phi + NB * W * M;
  short* outm16 = (short*)(filt + 64);
  short* ww16   = outm16 + (size_t)BB * W * 128;
  short* w116   = ww16 + NB * W * W;
  short* w1fc16 = w116 + NB * H * W;
  short* w0fc16 = w1fc16 + H * W;

  k_basis2<<<dim3((2 * 128 * XPAD + 255) / 256), 256, 0, stream>>>(basT16, basC16);
  k_prep2<<<dim3((16384 + 64 + 59392 + 255) / 256), 256, 0, stream>>>(
      log_dec, w_w, g_w1, fc1_w, fc0_w, a_w, expz, phi, filt, ww16, w116, w1fc16, w0fc16);
  k_fc0m<<<dim3(129, BB), 256, 0, stream>>>(x, grid, w0fc16, fc0_b, h16, hX);
  hipMemsetAsync(vhat, 0, (size_t)(BB * W * 128 + BB * H * 128) * sizeof(float), stream);

  for (int blk = 0; blk < NB; ++blk){
    k_dft<<<dim3(16, BB, 3), 256, 0, stream>>>(h16, hX, w116, g_b1, basT16, vhat, gmidhat, blk);
    k_ghat<<<dim3(BB, 32), 256, 0, stream>>>(gmidhat, g_w2, g_b2, a_g, ghat, blk);
    k_outm<<<dim3(64, BB), 256, 0, stream>>>(vhat, ghat, mix_re, mix_im, expz, phi, filt, outm16, blk);
    k_update<<<dim3(XPAD / 128, BB), 256, 0, stream>>>(h16, hX, outm16, basC16, ww16, w_b, a_w, blk);
  }
  k_fc12<<<dim3(X / 128, BB), 256, 0, stream>>>(hX, w1fc16, fc1_b, fc2_w, fc2_b, out);
}